// Round 10
// baseline (151.369 us; speedup 1.0000x reference)
//
#include <hip/hip_runtime.h>
#include <math.h>

typedef _Float16 h4 __attribute__((ext_vector_type(4)));
typedef _Float16 h2 __attribute__((ext_vector_type(2)));
typedef float    f4 __attribute__((ext_vector_type(4)));

namespace {
constexpr float LB = 4.5f;                       // HSGP half-domain
constexpr float WF = (float)M_PI / (2.0f * LB);  // base frequency
}

// ---------------------------------------------------------------------------
// Setup: build the 3 shared A-fragments for v_mfma_f32_16x16x16_f16.
// A_d[row=a][k=j] = beta[d, a*12+j] * sqrt(S(a,j)) / LB, padded to 16x16.
// Fragment layout: lane l holds A[l&15][4*(l>>4)+t], t=0..3.
// ---------------------------------------------------------------------------
__global__ void setup_A_kernel(const float* __restrict__ beta,
                               const float* __restrict__ ls,
                               const float* __restrict__ alpha,
                               _Float16* __restrict__ A) {
    int idx = blockIdx.x * blockDim.x + threadIdx.x;
    if (idx >= 768) return;
    int d = idx >> 8;
    int l = (idx >> 2) & 63;
    int t = idx & 3;
    int r = l & 15;                 // output row = a index
    int k = ((l >> 4) << 2) + t;    // K index   = j index
    float val = 0.0f;
    if (r < 12 && k < 12) {
        float w0 = WF * (float)(r + 1);
        float w1 = WF * (float)(k + 1);
        float l0 = ls[0], l1 = ls[1], al = alpha[0];
        float S = al * al * (2.0f * (float)M_PI) * l0 * l1 *
                  expf(-0.5f * (l0 * l0 * w0 * w0 + l1 * l1 * w1 * w1));
        val = beta[d * 144 + r * 12 + k] * sqrtf(S) * (1.0f / LB);
    }
    A[idx] = (_Float16)val;
}

// ---------------------------------------------------------------------------
// 4 consecutive multiples mb..mb+3 of angle th via HW sincos + angle-addition.
// ---------------------------------------------------------------------------
__device__ __forceinline__ void trig4(float th, float mb, float* s, float* c) {
    float s1 = __sinf(th), c1 = __cosf(th);
    float sb = __sinf(mb * th), cb = __cosf(mb * th);
    s[0] = sb; c[0] = cb;
    #pragma unroll
    for (int t = 1; t < 4; ++t) {
        s[t] = fmaf(s[t - 1], c1,  c[t - 1] * s1);
        c[t] = fmaf(c[t - 1], c1, -(s[t - 1] * s1));
    }
}

__device__ __forceinline__ h4 pack4(float a, float b, float c, float d) {
    h2 lo = __builtin_bit_cast(h2, __builtin_amdgcn_cvt_pkrtz(a, b));
    h2 hi = __builtin_bit_cast(h2, __builtin_amdgcn_cvt_pkrtz(c, d));
    return __builtin_shufflevector(lo, hi, 0, 1, 2, 3);
}

// ---------------------------------------------------------------------------
// Sum over the 4 lane-groups (rows of 16) — pure-VALU permlane butterflies,
// result valid in ALL 64 lanes. No LDS pipe, no lgkmcnt, no address setup.
//   permlane16_swap: a.rows{1,3} <-> b.rows{0,2}  (a=b=x -> a+b = row-pair sums)
//   permlane32_swap: c.rows{2,3} <-> d.rows{0,1}  (-> full sum everywhere)
// ---------------------------------------------------------------------------
__device__ __forceinline__ float cross_sum4(float x) {
    float a = x, b = x;
    asm("v_permlane16_swap_b32 %0, %1" : "+v"(a), "+v"(b));
    float s = a + b;
    float c = s, d = s;
    asm("v_permlane32_swap_b32 %0, %1" : "+v"(c), "+v"(d));
    return c + d;
}

// ---------------------------------------------------------------------------
// Main: one wave = 16 elements (element = lane&15, lane-group g = lane>>4
// owns a-rows 4g..4g+3). Per step:
//   stage 1 (matrix pipe): u_d = M_d * s1, w_d = M_d * wc1   (6 MFMAs)
//   per-lane fold (VALU):  f_d, dA_d, dB_d partials over this lane's 4 rows,
//                          vv-fold to q0p/q1p (element-uniform across groups)
//   cross_sum4 (VALU permlane): 5 reductions, full sums in every lane.
// Round 6 used ds_bpermute shuffles here (LDS pipe, ~300 serial cyc); round 9
// used 9 ones-MFMAs + 9 f16 packs (equal cost). permlane is the cheap path.
// ---------------------------------------------------------------------------
__global__ __launch_bounds__(64)
void geo_kernel(const float* __restrict__ xg, const float* __restrict__ vg,
                const _Float16* Ag /* non-restrict-ish: pinned below */,
                float* __restrict__ out, int B)
{
    int lane = threadIdx.x;
    int ebase = blockIdx.x << 4;
    if (ebase >= B) return;
    int g = lane >> 4;
    int e = ebase + (lane & 15);
    if (e >= B) e = B - 1;          // benign clamp (duplicate writes identical)

    // ---- shared A fragments (6 VGPRs) ----
    union U8 { uint2 u; h4 h; };
    const uint2* Au = reinterpret_cast<const uint2*>(Ag);
    U8 a0, a1, a2;
    a0.u = Au[0 * 64 + lane];
    a1.u = Au[1 * 64 + lane];
    a2.u = Au[2 * 64 + lane];
    asm volatile("" ::: "memory");  // forbid reload of Ag inside the loop
    h4 A0 = a0.h, A1 = a1.h, A2 = a2.h;

    float mb = (float)(4 * g + 1);
    float Wm[4];
    #pragma unroll
    for (int t = 0; t < 4; ++t) Wm[t] = WF * (mb + (float)t);

    float2 xv = reinterpret_cast<const float2*>(xg)[e];
    float2 vv2 = reinterpret_cast<const float2*>(vg)[e];
    float x0 = xv.x, x1 = xv.y, v0 = vv2.x, v1 = vv2.y;

    // per-lane output slot: out[t][g>>1][e][g&1]
    unsigned off = 4u * ((((unsigned)(g >> 1) * (unsigned)B) + (unsigned)e) * 2u
                         + (unsigned)(g & 1));
    const unsigned stride = 16u * (unsigned)B;   // bytes per time slot
    char* outc = reinterpret_cast<char*>(out);
    {
        float sval = (g & 2) ? ((g & 1) ? v1 : v0) : ((g & 1) ? x1 : x0);
        *reinterpret_cast<float*>(outc + off) = sval;
    }

    // Adams histories (older entries)
    float h1x = 0.f, h2x = 0.f, h3x = 0.f, h1y = 0.f, h2y = 0.f, h3y = 0.f;
    float g1x = 0.f, g2x = 0.f, g3x = 0.f, g1y = 0.f, g2y = 0.f, g3y = 0.f;
    const float h = 1.0f / 99.0f;

    auto STEP = [&](float c0, float c1c, float c2c, float c3c) {
        // ---- per-lane trig: multiples 4g+1..4g+4 of both dims ----
        float s0v[4], c0v[4], s1v[4], c1v[4], wc0[4];
        trig4(WF * (x0 + LB), mb, s0v, c0v);
        trig4(WF * (x1 + LB), mb, s1v, c1v);
        #pragma unroll
        for (int t = 0; t < 4; ++t) wc0[t] = Wm[t] * c0v[t];

        h4 bs = pack4(s1v[0], s1v[1], s1v[2], s1v[3]);
        h4 bc = pack4(Wm[0] * c1v[0], Wm[1] * c1v[1],
                      Wm[2] * c1v[2], Wm[3] * c1v[3]);

        // ---- stage 1: u_d = M_d*s1, w_d = M_d*wc1 ----
        f4 z = {0.f, 0.f, 0.f, 0.f};
        f4 u0 = __builtin_amdgcn_mfma_f32_16x16x16f16(A0, bs, z, 0, 0, 0);
        f4 u1 = __builtin_amdgcn_mfma_f32_16x16x16f16(A1, bs, z, 0, 0, 0);
        f4 u2 = __builtin_amdgcn_mfma_f32_16x16x16f16(A2, bs, z, 0, 0, 0);
        f4 w0 = __builtin_amdgcn_mfma_f32_16x16x16f16(A0, bc, z, 0, 0, 0);
        f4 w1 = __builtin_amdgcn_mfma_f32_16x16x16f16(A1, bc, z, 0, 0, 0);
        f4 w2 = __builtin_amdgcn_mfma_f32_16x16x16f16(A2, bc, z, 0, 0, 0);

        // ---- per-lane fold over this lane's 4 a-rows (rows 4g..4g+3) ----
        float f0 = 0.f, f1 = 0.f, f2 = 0.f;
        float dA0 = 0.f, dA1 = 0.f, dA2 = 0.f;
        float dB0 = 0.f, dB1 = 0.f, dB2 = 0.f;
        #pragma unroll
        for (int t = 0; t < 4; ++t) {
            float sA = s0v[t], cA = wc0[t];
            f0  = fmaf(sA, u0[t], f0);   dA0 = fmaf(cA, u0[t], dA0);
            f1  = fmaf(sA, u1[t], f1);   dA1 = fmaf(cA, u1[t], dA1);
            f2  = fmaf(sA, u2[t], f2);   dA2 = fmaf(cA, u2[t], dA2);
            dB0 = fmaf(sA, w0[t], dB0);
            dB1 = fmaf(sA, w1[t], dB1);
            dB2 = fmaf(sA, w2[t], dB2);
        }

        // ---- fold vv (element-uniform across lane-groups) pre-reduction ----
        float vv00 = v0 * v0, vv01 = v0 * v1, vv11 = v1 * v1;
        float q0p = dA0 * vv00 + 2.0f * dB0 * vv01 + fmaf(2.0f, dB1, -dA2) * vv11;
        float q1p = fmaf(2.0f, dA1, -dB0) * vv00 + 2.0f * dA2 * vv01 + dB2 * vv11;

        // ---- permlane reduction over the 4 lane-groups ----
        f0  = cross_sum4(f0);
        f1  = cross_sum4(f1);
        f2  = cross_sum4(f2);
        q0p = cross_sum4(q0p);
        q1p = cross_sum4(q1p);

        // ---- 2x2 Christoffel acceleration (lockstep on all lanes) ----
        float G00 = f0 + 1.0f, G01 = f1, G11 = f2 + 1.0f;
        float det = fmaf(G00, G11, -(G01 * G01));
        float rdet = __builtin_amdgcn_rcpf(det);
        float a0v = -0.5f * rdet * fmaf(G11, q0p, -(G01 * q1p));
        float a1v = -0.5f * rdet * fmaf(G00, q1p, -(G01 * q0p));

        // ---- Adams-Bashforth update ----
        float dx0 = fmaf(c0, v0, fmaf(c1c, h1x, fmaf(c2c, h2x, c3c * h3x)));
        float dx1 = fmaf(c0, v1, fmaf(c1c, h1y, fmaf(c2c, h2y, c3c * h3y)));
        float dv0 = fmaf(c0, a0v, fmaf(c1c, g1x, fmaf(c2c, g2x, c3c * g3x)));
        float dv1 = fmaf(c0, a1v, fmaf(c1c, g1y, fmaf(c2c, g2y, c3c * g3y)));
        h3x = h2x; h2x = h1x; h1x = v0;  h3y = h2y; h2y = h1y; h1y = v1;
        g3x = g2x; g2x = g1x; g1x = a0v; g3y = g2y; g2y = g1y; g1y = a1v;
        x0 = fmaf(h, dx0, x0); x1 = fmaf(h, dx1, x1);
        v0 = fmaf(h, dv0, v0); v1 = fmaf(h, dv1, v1);

        off += stride;
        float sval = (g & 2) ? ((g & 1) ? v1 : v0) : ((g & 1) ? x1 : x0);
        *reinterpret_cast<float*>(outc + off) = sval;
    };

    // startup (orders 1..3), then steady AB4 (96 = 24*4 iterations)
    STEP(1.0f, 0.0f, 0.0f, 0.0f);
    STEP(1.5f, -0.5f, 0.0f, 0.0f);
    STEP(23.0f / 12.0f, -16.0f / 12.0f, 5.0f / 12.0f, 0.0f);
    #pragma unroll 4
    for (int t = 3; t < 99; ++t)
        STEP(55.0f / 24.0f, -59.0f / 24.0f, 37.0f / 24.0f, -9.0f / 24.0f);
}

// ---------------------------------------------------------------------------
extern "C" void kernel_launch(void* const* d_in, const int* in_sizes, int n_in,
                              void* d_out, int out_size, void* d_ws, size_t ws_size,
                              hipStream_t stream) {
    const float* x0    = (const float*)d_in[0];
    const float* v0    = (const float*)d_in[1];
    const float* beta  = (const float*)d_in[2];
    const float* ls    = (const float*)d_in[3];
    const float* alpha = (const float*)d_in[4];
    float* out = (float*)d_out;
    _Float16* A = (_Float16*)d_ws;   // 768 halfs: 3 MFMA A-fragments

    int B = in_sizes[0] / 2;         // 50000

    hipLaunchKernelGGL(setup_A_kernel, dim3(12), dim3(64), 0, stream,
                       beta, ls, alpha, A);

    int grid = (B + 15) / 16;        // 3125 single-wave blocks
    hipLaunchKernelGGL(geo_kernel, dim3(grid), dim3(64), 0, stream,
                       x0, v0, A, out, B);
}

// Round 11
// 125.124 us; speedup vs baseline: 1.2097x; 1.2097x over previous
//
#include <hip/hip_runtime.h>
#include <math.h>

typedef _Float16 h4 __attribute__((ext_vector_type(4)));
typedef _Float16 h2 __attribute__((ext_vector_type(2)));
typedef float    f4 __attribute__((ext_vector_type(4)));

namespace {
constexpr float LB = 4.5f;                       // HSGP half-domain
constexpr float WF = (float)M_PI / (2.0f * LB);  // base frequency (rad)
constexpr float REV = 1.0f / (4.0f * LB);        // WF/(2*pi): radians->revolutions
}

// ---------------------------------------------------------------------------
// Setup: 6 shared A-fragments for v_mfma_f32_16x16x16_f16.
//   d2=0..2: A_d[a][j]  = beta[d,a*12+j]*sqrt(S(a,j))/LB          (for u = A*sin)
//   d2=3..5: A'_d[a][j] = A_d[a][j] * W*(j+1)                     (for w = A'*cos)
// Fragment layout: lane l holds A[l&15][4*(l>>4)+t], t=0..3.
// ---------------------------------------------------------------------------
__global__ void setup_A_kernel(const float* __restrict__ beta,
                               const float* __restrict__ ls,
                               const float* __restrict__ alpha,
                               _Float16* __restrict__ A) {
    int idx = blockIdx.x * blockDim.x + threadIdx.x;
    if (idx >= 1536) return;
    int d2 = idx >> 8;              // 0..5
    int d  = (d2 >= 3) ? d2 - 3 : d2;
    int l = (idx >> 2) & 63;
    int t = idx & 3;
    int r = l & 15;                 // output row = a index
    int k = ((l >> 4) << 2) + t;    // K index   = j index
    float val = 0.0f;
    if (r < 12 && k < 12) {
        float w0 = WF * (float)(r + 1);
        float w1 = WF * (float)(k + 1);
        float l0 = ls[0], l1 = ls[1], al = alpha[0];
        float S = al * al * (2.0f * (float)M_PI) * l0 * l1 *
                  expf(-0.5f * (l0 * l0 * w0 * w0 + l1 * l1 * w1 * w1));
        val = beta[d * 144 + r * 12 + k] * sqrtf(S) * (1.0f / LB);
        if (d2 >= 3) val *= WF * (float)(k + 1);   // bake j-frequency weight
    }
    A[idx] = (_Float16)val;
}

// ---------------------------------------------------------------------------
// 4 consecutive multiples mb..mb+3 of angle (2*pi*thr): HW trig in revolutions
// (no range-reduction muls; |mb*thr| << 256-rev valid domain) + angle-addition.
// ---------------------------------------------------------------------------
__device__ __forceinline__ void trig4r(float thr, float mb, float* s, float* c) {
    float s1 = __builtin_amdgcn_sinf(thr);
    float c1 = __builtin_amdgcn_cosf(thr);
    float mbr = mb * thr;
    s[0] = __builtin_amdgcn_sinf(mbr);
    c[0] = __builtin_amdgcn_cosf(mbr);
    #pragma unroll
    for (int t = 1; t < 4; ++t) {
        s[t] = fmaf(s[t - 1], c1,  c[t - 1] * s1);
        c[t] = fmaf(c[t - 1], c1, -(s[t - 1] * s1));
    }
}

__device__ __forceinline__ h4 pack4(float a, float b, float c, float d) {
    h2 lo = __builtin_bit_cast(h2, __builtin_amdgcn_cvt_pkrtz(a, b));
    h2 hi = __builtin_bit_cast(h2, __builtin_amdgcn_cvt_pkrtz(c, d));
    return __builtin_shufflevector(lo, hi, 0, 1, 2, 3);
}

// ---------------------------------------------------------------------------
// Main: one wave = 16 elements (element = lane&15, lane-group g = lane>>4 owns
// a-rows 4g..4g+3). Stage 1 (matrix pipe): u_d = A_d*sin1, w_d = A'_d*cos1.
// Per-lane fold (36 FMA) + vv pre-fold; cross-group sums via __shfl_xor
// (ds pipe — measured cheapest: R6=139 vs permlane R10=151, ones-MFMA R9=145).
// ---------------------------------------------------------------------------
__global__ __launch_bounds__(64)
void geo_kernel(const float* __restrict__ xg, const float* __restrict__ vg,
                const _Float16* Ag /* non-restrict-ish: pinned below */,
                float* __restrict__ out, int B)
{
    int lane = threadIdx.x;
    int ebase = blockIdx.x << 4;
    if (ebase >= B) return;
    int g = lane >> 4;
    int e = ebase + (lane & 15);
    if (e >= B) e = B - 1;          // benign clamp (duplicate writes identical)

    // ---- shared A fragments (12 VGPRs) ----
    union U8 { uint2 u; h4 h; };
    const uint2* Au = reinterpret_cast<const uint2*>(Ag);
    U8 a0, a1, a2, a3, a4, a5;
    a0.u = Au[0 * 64 + lane];
    a1.u = Au[1 * 64 + lane];
    a2.u = Au[2 * 64 + lane];
    a3.u = Au[3 * 64 + lane];
    a4.u = Au[4 * 64 + lane];
    a5.u = Au[5 * 64 + lane];
    asm volatile("" ::: "memory");  // forbid reload of Ag inside the loop
    h4 A0 = a0.h, A1 = a1.h, A2 = a2.h;
    h4 A3 = a3.h, A4 = a4.h, A5 = a5.h;

    float mb = (float)(4 * g + 1);
    float Wm[4];
    #pragma unroll
    for (int t = 0; t < 4; ++t) Wm[t] = WF * (mb + (float)t);

    float2 xv = reinterpret_cast<const float2*>(xg)[e];
    float2 vv2 = reinterpret_cast<const float2*>(vg)[e];
    float x0 = xv.x, x1 = xv.y, v0 = vv2.x, v1 = vv2.y;

    // per-lane output slot: out[t][g>>1][e][g&1]
    unsigned off = 4u * ((((unsigned)(g >> 1) * (unsigned)B) + (unsigned)e) * 2u
                         + (unsigned)(g & 1));
    const unsigned stride = 16u * (unsigned)B;   // bytes per time slot
    char* outc = reinterpret_cast<char*>(out);
    {
        float sval = (g & 2) ? ((g & 1) ? v1 : v0) : ((g & 1) ? x1 : x0);
        *reinterpret_cast<float*>(outc + off) = sval;
    }

    // Adams histories (older entries)
    float h1x = 0.f, h2x = 0.f, h3x = 0.f, h1y = 0.f, h2y = 0.f, h3y = 0.f;
    float g1x = 0.f, g2x = 0.f, g3x = 0.f, g1y = 0.f, g2y = 0.f, g3y = 0.f;
    const float h = 1.0f / 99.0f;

    auto STEP = [&](float hc0, float hc1, float hc2, float hc3) {
        // ---- per-lane trig (revolutions): multiples 4g+1..4g+4, both dims ----
        float s0v[4], c0v[4], s1v[4], c1v[4], wc0[4];
        trig4r(fmaf(x0, REV, LB * REV), mb, s0v, c0v);
        trig4r(fmaf(x1, REV, LB * REV), mb, s1v, c1v);
        #pragma unroll
        for (int t = 0; t < 4; ++t) wc0[t] = Wm[t] * c0v[t];

        h4 bs = pack4(s1v[0], s1v[1], s1v[2], s1v[3]);
        h4 bc = pack4(c1v[0], c1v[1], c1v[2], c1v[3]);   // weights baked in A3..A5

        // ---- stage 1: u_d = A_d*sin1, w_d = A'_d*cos1 ----
        f4 z = {0.f, 0.f, 0.f, 0.f};
        f4 u0 = __builtin_amdgcn_mfma_f32_16x16x16f16(A0, bs, z, 0, 0, 0);
        f4 u1 = __builtin_amdgcn_mfma_f32_16x16x16f16(A1, bs, z, 0, 0, 0);
        f4 u2 = __builtin_amdgcn_mfma_f32_16x16x16f16(A2, bs, z, 0, 0, 0);
        f4 w0 = __builtin_amdgcn_mfma_f32_16x16x16f16(A3, bc, z, 0, 0, 0);
        f4 w1 = __builtin_amdgcn_mfma_f32_16x16x16f16(A4, bc, z, 0, 0, 0);
        f4 w2 = __builtin_amdgcn_mfma_f32_16x16x16f16(A5, bc, z, 0, 0, 0);

        // ---- per-lane fold over this lane's 4 a-rows ----
        float f0 = 0.f, f1 = 0.f, f2 = 0.f;
        float dA0 = 0.f, dA1 = 0.f, dA2 = 0.f;
        float dB0 = 0.f, dB1 = 0.f, dB2 = 0.f;
        #pragma unroll
        for (int t = 0; t < 4; ++t) {
            float sA = s0v[t], cA = wc0[t];
            f0  = fmaf(sA, u0[t], f0);   dA0 = fmaf(cA, u0[t], dA0);
            f1  = fmaf(sA, u1[t], f1);   dA1 = fmaf(cA, u1[t], dA1);
            f2  = fmaf(sA, u2[t], f2);   dA2 = fmaf(cA, u2[t], dA2);
            dB0 = fmaf(sA, w0[t], dB0);
            dB1 = fmaf(sA, w1[t], dB1);
            dB2 = fmaf(sA, w2[t], dB2);
        }

        // ---- fold vv (element-uniform across lane-groups) pre-reduction ----
        float vv00 = v0 * v0, vv01 = v0 * v1, vv11 = v1 * v1;
        float q0p = dA0 * vv00 + 2.0f * dB0 * vv01 + fmaf(2.0f, dB1, -dA2) * vv11;
        float q1p = fmaf(2.0f, dA1, -dB0) * vv00 + 2.0f * dA2 * vv01 + dB2 * vv11;

        // ---- cross-group sums on the ds pipe (overlaps VALU of other waves) --
        f0  += __shfl_xor(f0, 16);  f0  += __shfl_xor(f0, 32);
        f1  += __shfl_xor(f1, 16);  f1  += __shfl_xor(f1, 32);
        f2  += __shfl_xor(f2, 16);  f2  += __shfl_xor(f2, 32);
        q0p += __shfl_xor(q0p, 16); q0p += __shfl_xor(q0p, 32);
        q1p += __shfl_xor(q1p, 16); q1p += __shfl_xor(q1p, 32);

        // ---- 2x2 Christoffel acceleration (lockstep on all lanes) ----
        float G00 = f0 + 1.0f, G01 = f1, G11 = f2 + 1.0f;
        float det = fmaf(G00, G11, -(G01 * G01));
        float rdet = __builtin_amdgcn_rcpf(det);
        float a0v = -0.5f * rdet * fmaf(G11, q0p, -(G01 * q1p));
        float a1v = -0.5f * rdet * fmaf(G00, q1p, -(G01 * q0p));

        // ---- Adams-Bashforth update, h baked into coeffs: 4 FMA per state ----
        x0 = fmaf(hc0, v0, fmaf(hc1, h1x, fmaf(hc2, h2x, fmaf(hc3, h3x, x0))));
        x1 = fmaf(hc0, v1, fmaf(hc1, h1y, fmaf(hc2, h2y, fmaf(hc3, h3y, x1))));
        float nv0 = fmaf(hc0, a0v, fmaf(hc1, g1x, fmaf(hc2, g2x, fmaf(hc3, g3x, v0))));
        float nv1 = fmaf(hc0, a1v, fmaf(hc1, g1y, fmaf(hc2, g2y, fmaf(hc3, g3y, v1))));
        h3x = h2x; h2x = h1x; h1x = v0;  h3y = h2y; h2y = h1y; h1y = v1;
        g3x = g2x; g2x = g1x; g1x = a0v; g3y = g2y; g2y = g1y; g1y = a1v;
        v0 = nv0; v1 = nv1;

        off += stride;
        float sval = (g & 2) ? ((g & 1) ? v1 : v0) : ((g & 1) ? x1 : x0);
        *reinterpret_cast<float*>(outc + off) = sval;
    };

    // startup (orders 1..3), then steady AB4 (96 = 24*4 iterations)
    STEP(h * 1.0f, 0.0f, 0.0f, 0.0f);
    STEP(h * 1.5f, h * -0.5f, 0.0f, 0.0f);
    STEP(h * 23.0f / 12.0f, h * -16.0f / 12.0f, h * 5.0f / 12.0f, 0.0f);
    #pragma unroll 4
    for (int t = 3; t < 99; ++t)
        STEP(h * 55.0f / 24.0f, h * -59.0f / 24.0f, h * 37.0f / 24.0f, h * -9.0f / 24.0f);
}

// ---------------------------------------------------------------------------
extern "C" void kernel_launch(void* const* d_in, const int* in_sizes, int n_in,
                              void* d_out, int out_size, void* d_ws, size_t ws_size,
                              hipStream_t stream) {
    const float* x0    = (const float*)d_in[0];
    const float* v0    = (const float*)d_in[1];
    const float* beta  = (const float*)d_in[2];
    const float* ls    = (const float*)d_in[3];
    const float* alpha = (const float*)d_in[4];
    float* out = (float*)d_out;
    _Float16* A = (_Float16*)d_ws;   // 1536 halfs: 6 MFMA A-fragments

    int B = in_sizes[0] / 2;         // 50000

    hipLaunchKernelGGL(setup_A_kernel, dim3(24), dim3(64), 0, stream,
                       beta, ls, alpha, A);

    int grid = (B + 15) / 16;        // 3125 single-wave blocks
    hipLaunchKernelGGL(geo_kernel, dim3(grid), dim3(64), 0, stream,
                       x0, v0, A, out, B);
}

// Round 12
// 122.843 us; speedup vs baseline: 1.2322x; 1.0186x over previous
//
#include <hip/hip_runtime.h>
#include <math.h>

typedef _Float16 h4 __attribute__((ext_vector_type(4)));
typedef _Float16 h2 __attribute__((ext_vector_type(2)));
typedef float    f4 __attribute__((ext_vector_type(4)));

namespace {
constexpr float LB = 4.5f;                       // HSGP half-domain
constexpr float WF = (float)M_PI / (2.0f * LB);  // base frequency (rad)
constexpr float REV = 1.0f / (4.0f * LB);        // WF/(2*pi): radians->revolutions
}

// ---------------------------------------------------------------------------
// Setup: 7 shared A-fragments for v_mfma_f32_16x16x16_f16.
//   d2=0..2: A_d[a][j]  = beta[d,a*12+j]*sqrt(S(a,j))/LB       (u = A*sin)
//   d2=3..5: A'_d[a][j] = A_d[a][j] * W*(j+1)                  (w = A'*cos)
//   d2=6   : selector A_sel[r][k] = (k%4 == r%4) ? 1 : 0       (cross-group sum:
//            D[r][c] = sum_g B[4g+(r%4)][c] -> acc reg t = full sum of qty t)
// Fragment layout: lane l holds A[l&15][4*(l>>4)+t], t=0..3.
// ---------------------------------------------------------------------------
__global__ void setup_A_kernel(const float* __restrict__ beta,
                               const float* __restrict__ ls,
                               const float* __restrict__ alpha,
                               _Float16* __restrict__ A) {
    int idx = blockIdx.x * blockDim.x + threadIdx.x;
    if (idx >= 1792) return;
    int d2 = idx >> 8;              // 0..6
    int l = (idx >> 2) & 63;
    int t = idx & 3;
    int r = l & 15;                 // output row
    int k = ((l >> 4) << 2) + t;    // K index
    float val = 0.0f;
    if (d2 == 6) {
        val = ((k & 3) == (r & 3)) ? 1.0f : 0.0f;
    } else if (r < 12 && k < 12) {
        int d = (d2 >= 3) ? d2 - 3 : d2;
        float w0 = WF * (float)(r + 1);
        float w1 = WF * (float)(k + 1);
        float l0 = ls[0], l1 = ls[1], al = alpha[0];
        float S = al * al * (2.0f * (float)M_PI) * l0 * l1 *
                  expf(-0.5f * (l0 * l0 * w0 * w0 + l1 * l1 * w1 * w1));
        val = beta[d * 144 + r * 12 + k] * sqrtf(S) * (1.0f / LB);
        if (d2 >= 3) val *= WF * (float)(k + 1);   // bake j-frequency weight
    }
    A[idx] = (_Float16)val;
}

// ---------------------------------------------------------------------------
// 4 consecutive multiples mb..mb+3 of angle (2*pi*thr): HW trig in revolutions
// (no range-reduction muls) + angle-addition recurrence.
// ---------------------------------------------------------------------------
__device__ __forceinline__ void trig4r(float thr, float mb, float* s, float* c) {
    float s1 = __builtin_amdgcn_sinf(thr);
    float c1 = __builtin_amdgcn_cosf(thr);
    float mbr = mb * thr;
    s[0] = __builtin_amdgcn_sinf(mbr);
    c[0] = __builtin_amdgcn_cosf(mbr);
    #pragma unroll
    for (int t = 1; t < 4; ++t) {
        s[t] = fmaf(s[t - 1], c1,  c[t - 1] * s1);
        c[t] = fmaf(c[t - 1], c1, -(s[t - 1] * s1));
    }
}

__device__ __forceinline__ h4 pack4(float a, float b, float c, float d) {
    h2 lo = __builtin_bit_cast(h2, __builtin_amdgcn_cvt_pkrtz(a, b));
    h2 hi = __builtin_bit_cast(h2, __builtin_amdgcn_cvt_pkrtz(c, d));
    return __builtin_shufflevector(lo, hi, 0, 1, 2, 3);
}

// ---------------------------------------------------------------------------
// Main: one wave = 16 elements (element = lane&15, lane-group g = lane>>4 owns
// a-rows 4g..4g+3). Per step:
//   stage 1 (matrix pipe): u_d = A_d*sin1, w_d = A'_d*cos1       (6 MFMAs)
//   per-lane fold (36 FMA) + vv pre-fold -> 5 per-lane partials
//   stage 2 (matrix pipe): selector-MFMA reduces (f0,f1,f2,q0) and (q1) —
//     acc reg t of EVERY lane = full cross-group sum of quantity t. Replaces
//     R6/R11's 10 shfl_xor (2 serial ds round-trips on the critical path).
// ---------------------------------------------------------------------------
__global__ __launch_bounds__(64)
void geo_kernel(const float* __restrict__ xg, const float* __restrict__ vg,
                const _Float16* Ag /* non-restrict-ish: pinned below */,
                float* __restrict__ out, int B)
{
    int lane = threadIdx.x;
    int ebase = blockIdx.x << 4;
    if (ebase >= B) return;
    int g = lane >> 4;
    int e = ebase + (lane & 15);
    if (e >= B) e = B - 1;          // benign clamp (duplicate writes identical)

    // ---- shared A fragments (14 VGPRs) ----
    union U8 { uint2 u; h4 h; };
    const uint2* Au = reinterpret_cast<const uint2*>(Ag);
    U8 a0, a1, a2, a3, a4, a5, a6;
    a0.u = Au[0 * 64 + lane];
    a1.u = Au[1 * 64 + lane];
    a2.u = Au[2 * 64 + lane];
    a3.u = Au[3 * 64 + lane];
    a4.u = Au[4 * 64 + lane];
    a5.u = Au[5 * 64 + lane];
    a6.u = Au[6 * 64 + lane];
    asm volatile("" ::: "memory");  // forbid reload of Ag inside the loop
    h4 A0 = a0.h, A1 = a1.h, A2 = a2.h;
    h4 A3 = a3.h, A4 = a4.h, A5 = a5.h;
    h4 SEL = a6.h;

    float mb = (float)(4 * g + 1);
    float Wm[4];
    #pragma unroll
    for (int t = 0; t < 4; ++t) Wm[t] = WF * (mb + (float)t);

    float2 xv = reinterpret_cast<const float2*>(xg)[e];
    float2 vv2 = reinterpret_cast<const float2*>(vg)[e];
    float x0 = xv.x, x1 = xv.y, v0 = vv2.x, v1 = vv2.y;

    // per-lane output slot: out[t][g>>1][e][g&1]
    unsigned off = 4u * ((((unsigned)(g >> 1) * (unsigned)B) + (unsigned)e) * 2u
                         + (unsigned)(g & 1));
    const unsigned stride = 16u * (unsigned)B;   // bytes per time slot
    char* outc = reinterpret_cast<char*>(out);
    {
        float sval = (g & 2) ? ((g & 1) ? v1 : v0) : ((g & 1) ? x1 : x0);
        *reinterpret_cast<float*>(outc + off) = sval;
    }

    // Adams histories (older entries)
    float h1x = 0.f, h2x = 0.f, h3x = 0.f, h1y = 0.f, h2y = 0.f, h3y = 0.f;
    float g1x = 0.f, g2x = 0.f, g3x = 0.f, g1y = 0.f, g2y = 0.f, g3y = 0.f;
    const float h = 1.0f / 99.0f;

    auto STEP = [&](float hc0, float hc1, float hc2, float hc3) {
        // ---- per-lane trig (revolutions): multiples 4g+1..4g+4, both dims ----
        float s0v[4], c0v[4], s1v[4], c1v[4], wc0[4];
        trig4r(fmaf(x0, REV, LB * REV), mb, s0v, c0v);
        trig4r(fmaf(x1, REV, LB * REV), mb, s1v, c1v);
        #pragma unroll
        for (int t = 0; t < 4; ++t) wc0[t] = Wm[t] * c0v[t];

        h4 bs = pack4(s1v[0], s1v[1], s1v[2], s1v[3]);
        h4 bc = pack4(c1v[0], c1v[1], c1v[2], c1v[3]);   // weights baked in A3..A5

        // ---- stage 1: u_d = A_d*sin1, w_d = A'_d*cos1 ----
        f4 z = {0.f, 0.f, 0.f, 0.f};
        f4 u0 = __builtin_amdgcn_mfma_f32_16x16x16f16(A0, bs, z, 0, 0, 0);
        f4 u1 = __builtin_amdgcn_mfma_f32_16x16x16f16(A1, bs, z, 0, 0, 0);
        f4 u2 = __builtin_amdgcn_mfma_f32_16x16x16f16(A2, bs, z, 0, 0, 0);
        f4 w0 = __builtin_amdgcn_mfma_f32_16x16x16f16(A3, bc, z, 0, 0, 0);
        f4 w1 = __builtin_amdgcn_mfma_f32_16x16x16f16(A4, bc, z, 0, 0, 0);
        f4 w2 = __builtin_amdgcn_mfma_f32_16x16x16f16(A5, bc, z, 0, 0, 0);

        // ---- per-lane fold over this lane's 4 a-rows ----
        float f0 = 0.f, f1 = 0.f, f2 = 0.f;
        float dA0 = 0.f, dA1 = 0.f, dA2 = 0.f;
        float dB0 = 0.f, dB1 = 0.f, dB2 = 0.f;
        #pragma unroll
        for (int t = 0; t < 4; ++t) {
            float sA = s0v[t], cA = wc0[t];
            f0  = fmaf(sA, u0[t], f0);   dA0 = fmaf(cA, u0[t], dA0);
            f1  = fmaf(sA, u1[t], f1);   dA1 = fmaf(cA, u1[t], dA1);
            f2  = fmaf(sA, u2[t], f2);   dA2 = fmaf(cA, u2[t], dA2);
            dB0 = fmaf(sA, w0[t], dB0);
            dB1 = fmaf(sA, w1[t], dB1);
            dB2 = fmaf(sA, w2[t], dB2);
        }

        // ---- fold vv (element-uniform across lane-groups) pre-reduction ----
        float vv00 = v0 * v0, vv11 = v1 * v1;
        float w01 = 2.0f * v0 * v1;
        float q0p = fmaf(dA0, vv00, fmaf(dB0, w01, fmaf(2.0f, dB1, -dA2) * vv11));
        float q1p = fmaf(fmaf(2.0f, dA1, -dB0), vv00, fmaf(dA2, w01, dB2 * vv11));

        // ---- stage 2: selector-MFMA cross-group reduction (no shuffles) ----
        h4 r1 = pack4(f0, f1, f2, q0p);
        h4 r2 = pack4(q1p, 0.0f, 0.0f, 0.0f);
        f4 D1 = __builtin_amdgcn_mfma_f32_16x16x16f16(SEL, r1, z, 0, 0, 0);
        f4 D2 = __builtin_amdgcn_mfma_f32_16x16x16f16(SEL, r2, z, 0, 0, 0);
        // acc reg t = sum over lane-groups of quantity t (valid in all lanes)
        float F0 = D1[0], F1 = D1[1], F2 = D1[2], Q0 = D1[3], Q1 = D2[0];

        // ---- 2x2 Christoffel acceleration (lockstep on all lanes) ----
        float G00 = F0 + 1.0f, G01 = F1, G11 = F2 + 1.0f;
        float det = fmaf(G00, G11, -(G01 * G01));
        float rdet = __builtin_amdgcn_rcpf(det);
        float a0v = -0.5f * rdet * fmaf(G11, Q0, -(G01 * Q1));
        float a1v = -0.5f * rdet * fmaf(G00, Q1, -(G01 * Q0));

        // ---- Adams-Bashforth update, h baked into coeffs: 4 FMA per state ----
        x0 = fmaf(hc0, v0, fmaf(hc1, h1x, fmaf(hc2, h2x, fmaf(hc3, h3x, x0))));
        x1 = fmaf(hc0, v1, fmaf(hc1, h1y, fmaf(hc2, h2y, fmaf(hc3, h3y, x1))));
        float nv0 = fmaf(hc0, a0v, fmaf(hc1, g1x, fmaf(hc2, g2x, fmaf(hc3, g3x, v0))));
        float nv1 = fmaf(hc0, a1v, fmaf(hc1, g1y, fmaf(hc2, g2y, fmaf(hc3, g3y, v1))));
        h3x = h2x; h2x = h1x; h1x = v0;  h3y = h2y; h2y = h1y; h1y = v1;
        g3x = g2x; g2x = g1x; g1x = a0v; g3y = g2y; g2y = g1y; g1y = a1v;
        v0 = nv0; v1 = nv1;

        off += stride;
        float sval = (g & 2) ? ((g & 1) ? v1 : v0) : ((g & 1) ? x1 : x0);
        *reinterpret_cast<float*>(outc + off) = sval;
    };

    // startup (orders 1..3), then steady AB4 (96 = 24*4 iterations)
    STEP(h * 1.0f, 0.0f, 0.0f, 0.0f);
    STEP(h * 1.5f, h * -0.5f, 0.0f, 0.0f);
    STEP(h * 23.0f / 12.0f, h * -16.0f / 12.0f, h * 5.0f / 12.0f, 0.0f);
    #pragma unroll 4
    for (int t = 3; t < 99; ++t)
        STEP(h * 55.0f / 24.0f, h * -59.0f / 24.0f, h * 37.0f / 24.0f, h * -9.0f / 24.0f);
}

// ---------------------------------------------------------------------------
extern "C" void kernel_launch(void* const* d_in, const int* in_sizes, int n_in,
                              void* d_out, int out_size, void* d_ws, size_t ws_size,
                              hipStream_t stream) {
    const float* x0    = (const float*)d_in[0];
    const float* v0    = (const float*)d_in[1];
    const float* beta  = (const float*)d_in[2];
    const float* ls    = (const float*)d_in[3];
    const float* alpha = (const float*)d_in[4];
    float* out = (float*)d_out;
    _Float16* A = (_Float16*)d_ws;   // 1792 halfs: 7 MFMA A-fragments

    int B = in_sizes[0] / 2;         // 50000

    hipLaunchKernelGGL(setup_A_kernel, dim3(28), dim3(64), 0, stream,
                       beta, ls, alpha, A);

    int grid = (B + 15) / 16;        // 3125 single-wave blocks
    hipLaunchKernelGGL(geo_kernel, dim3(grid), dim3(64), 0, stream,
                       x0, v0, A, out, B);
}